// Round 1
// baseline (664.426 us; speedup 1.0000x reference)
//
#include <hip/hip_runtime.h>

#define NB 4          // batch
#define C_IN 64
#define N_IN 8192
#define N_OUT 8192
#define D1 4
#define FS 15
#define HSZ 16384     // max hash cnt
#define C_MID 64
#define C_OUT 64
#define LEAK 0.01f

// workspace layout (float offsets)
#define SPLAT_OFF  0
#define SPLAT_SZ   (NB*(HSZ+1)*64)          // 4,194,560
#define ONES_OFF   (SPLAT_OFF + SPLAT_SZ)
#define ONES_SZ    (NB*(HSZ+1))             // 65,540
#define W0T_OFF    (ONES_OFF + ONES_SZ)
#define W0T_SZ     (C_MID*C_IN*FS)          // 61,440
#define W1T_OFF    (W0T_OFF + W0T_SZ)
#define W1T_SZ     (C_OUT*C_MID)            // 4,096
#define FB_OFF     (W1T_OFF + W1T_SZ)
#define FB_SZ      (NB*HSZ*64)              // 4,194,304

// ---------------------------------------------------------------------------
// W0t[f][c][o] = W0[o][c][f];  W1t[o][p] = W1[p][o]
__global__ __launch_bounds__(256) void transpose_w(const float* __restrict__ W0,
                                                   const float* __restrict__ W1,
                                                   float* __restrict__ W0t,
                                                   float* __restrict__ W1t) {
    int e = blockIdx.x * 256 + threadIdx.x;
    if (e < W0T_SZ) {
        int f = e / (64 * 64);
        int r = e % (64 * 64);
        int c = r >> 6;
        int o = r & 63;
        W0t[e] = W0[o * (C_IN * FS) + c * FS + f];
    } else {
        int e2 = e - W0T_SZ;   // < 4096
        int o = e2 >> 6, p = e2 & 63;
        W1t[e2] = W1[p * 64 + o];
    }
}

// ---------------------------------------------------------------------------
// splat: scatter-add barycentric-weighted features onto lattice vertices.
// block = 256 threads handles 64 points; lane = point, 4 channel-groups.
__global__ __launch_bounds__(256) void splat_kernel(const float* __restrict__ feat,
                                                    const float* __restrict__ bary,
                                                    const int* __restrict__ off,
                                                    float* __restrict__ splat,
                                                    float* __restrict__ ones) {
    int nl = threadIdx.x & 63;
    int cg = threadIdx.x >> 6;           // 0..3
    int pt = blockIdx.x * 64 + nl;       // global point in [0, NB*N_IN)
    int b  = pt / N_IN;
    int n  = pt - b * N_IN;

    int   idx[D1];
    float w[D1];
#pragma unroll
    for (int j = 0; j < D1; ++j) {
        idx[j] = off[(b * D1 + j) * N_IN + n] + 1;   // global row incl. batch base
        w[j]   = bary[(b * D1 + j) * N_IN + n];
    }
    if (cg == 0) {
#pragma unroll
        for (int j = 0; j < D1; ++j) atomicAdd(&ones[idx[j]], w[j]);
    }
    int c0 = cg * 16;
#pragma unroll
    for (int c = 0; c < 16; ++c) {
        float f = feat[((size_t)(b * 64 + c0 + c)) * N_IN + n];
#pragma unroll
        for (int j = 0; j < D1; ++j)
            atomicAdd(&splat[(size_t)idx[j] * 64 + c0 + c], w[j] * f);
    }
}

// ---------------------------------------------------------------------------
__global__ __launch_bounds__(256) void normalize_kernel(float* __restrict__ splat,
                                                        const float* __restrict__ ones) {
    int i = blockIdx.x * 256 + threadIdx.x;    // exactly SPLAT_SZ threads
    splat[i] = splat[i] / (ones[i >> 6] + 1e-5f);
}

// ---------------------------------------------------------------------------
// blur: per block computes fb[b, hb..hb+63, 0..63] =
//   W1 @ leaky(W0 (x) gathered-splat + b0) + b1
// 256 threads, 4x4 micro-tile, LDS tiles padded to 68 dwords/row.
__global__ __launch_bounds__(256) void blur_kernel(const float* __restrict__ splat,
                                                   const int* __restrict__ nbr,
                                                   const float* __restrict__ W0t,
                                                   const float* __restrict__ W1t,
                                                   const float* __restrict__ b0,
                                                   const float* __restrict__ b1,
                                                   float* __restrict__ fb) {
    __shared__ float As[64 * 68];
    __shared__ float Xs[64 * 68];
    __shared__ float Hs[64 * 68];

    const int tid = threadIdx.x;
    const int b   = blockIdx.x >> 8;           // 256 h-tiles per batch
    const int hb  = (blockIdx.x & 255) << 6;

    const int to = tid & 15;                   // o/p micro-tile (4 each)
    const int th = tid >> 4;                   // h  micro-tile (4 each)

    const int s_o  = tid & 63;                 // A-staging: o lane
    const int s_cb = (tid >> 6) * 16;          // A-staging: c base
    const int x_hh = tid & 63;                 // X-staging: h lane
    const int x_cq = tid >> 6;                 // X-staging: c quarter

    const size_t bbase = (size_t)b * (HSZ + 1) * 64;

    float acc[4][4] = {};

    for (int f = 0; f < FS; ++f) {
        __syncthreads();
        // stage A: As[c][o] = W0t[f][c][o]  (coalesced)
        const float* w0f = W0t + f * 4096;
#pragma unroll
        for (int i = 0; i < 16; ++i) {
            int c = s_cb + i;
            As[c * 68 + s_o] = w0f[c * 64 + s_o];
        }
        // stage X: Xs[c][hh] = splat[b, nbr(f,hb+hh)+1, c]
        int v = nbr[((b * FS) + f) * HSZ + hb + x_hh] + 1;
        const float* row = splat + bbase + (size_t)v * 64;
#pragma unroll
        for (int i = 0; i < 4; ++i) {
            int c0 = x_cq * 16 + i * 4;
            float4 val = *(const float4*)(row + c0);
            Xs[(c0 + 0) * 68 + x_hh] = val.x;
            Xs[(c0 + 1) * 68 + x_hh] = val.y;
            Xs[(c0 + 2) * 68 + x_hh] = val.z;
            Xs[(c0 + 3) * 68 + x_hh] = val.w;
        }
        __syncthreads();
#pragma unroll 4
        for (int k = 0; k < 64; ++k) {
            const float4 a = *(const float4*)(As + k * 68 + (to << 2));
            const float4 x = *(const float4*)(Xs + k * 68 + (th << 2));
            acc[0][0] += a.x * x.x; acc[0][1] += a.x * x.y; acc[0][2] += a.x * x.z; acc[0][3] += a.x * x.w;
            acc[1][0] += a.y * x.x; acc[1][1] += a.y * x.y; acc[1][2] += a.y * x.z; acc[1][3] += a.y * x.w;
            acc[2][0] += a.z * x.x; acc[2][1] += a.z * x.y; acc[2][2] += a.z * x.z; acc[2][3] += a.z * x.w;
            acc[3][0] += a.w * x.x; acc[3][1] += a.w * x.y; acc[3][2] += a.w * x.z; acc[3][3] += a.w * x.w;
        }
    }

    __syncthreads();
    // bias + leaky -> Hs[o][hh]; restage As = W1t[o][p]
    float4 b0v = *(const float4*)(b0 + (to << 2));
    const float b0a[4] = {b0v.x, b0v.y, b0v.z, b0v.w};
#pragma unroll
    for (int i = 0; i < 4; ++i) {
        float4 hv;
        float v0 = acc[i][0] + b0a[i]; hv.x = v0 > 0.f ? v0 : LEAK * v0;
        float v1 = acc[i][1] + b0a[i]; hv.y = v1 > 0.f ? v1 : LEAK * v1;
        float v2 = acc[i][2] + b0a[i]; hv.z = v2 > 0.f ? v2 : LEAK * v2;
        float v3 = acc[i][3] + b0a[i]; hv.w = v3 > 0.f ? v3 : LEAK * v3;
        *(float4*)(Hs + (to * 4 + i) * 68 + (th << 2)) = hv;
    }
#pragma unroll
    for (int i = 0; i < 16; ++i) {
        int o = s_cb + i;
        As[o * 68 + s_o] = W1t[o * 64 + s_o];
    }
    __syncthreads();

    float acc2[4][4] = {};
#pragma unroll 4
    for (int k = 0; k < 64; ++k) {
        const float4 a = *(const float4*)(As + k * 68 + (to << 2));  // W1[p][k]
        const float4 x = *(const float4*)(Hs + k * 68 + (th << 2));
        acc2[0][0] += a.x * x.x; acc2[0][1] += a.x * x.y; acc2[0][2] += a.x * x.z; acc2[0][3] += a.x * x.w;
        acc2[1][0] += a.y * x.x; acc2[1][1] += a.y * x.y; acc2[1][2] += a.y * x.z; acc2[1][3] += a.y * x.w;
        acc2[2][0] += a.z * x.x; acc2[2][1] += a.z * x.y; acc2[2][2] += a.z * x.z; acc2[2][3] += a.z * x.w;
        acc2[3][0] += a.w * x.x; acc2[3][1] += a.w * x.y; acc2[3][2] += a.w * x.z; acc2[3][3] += a.w * x.w;
    }

    float4 b1v = *(const float4*)(b1 + (to << 2));
#pragma unroll
    for (int j = 0; j < 4; ++j) {
        int h = hb + (th << 2) + j;
        float4 o4;
        o4.x = acc2[0][j] + b1v.x;
        o4.y = acc2[1][j] + b1v.y;
        o4.z = acc2[2][j] + b1v.z;
        o4.w = acc2[3][j] + b1v.w;
        *(float4*)(fb + ((size_t)b * HSZ + h) * 64 + (to << 2)) = o4;
    }
}

// ---------------------------------------------------------------------------
// slice: out[b,p,n] = bias[p] + sum_j ob[b,j,n] * fb[b, off[b,j,n], p]
// block = 256 threads (4 waves) handles 64 output points of one batch.
__global__ __launch_bounds__(256) void slice_kernel(const float* __restrict__ fb,
                                                    const float* __restrict__ ob,
                                                    const int* __restrict__ off,
                                                    const float* __restrict__ bias,
                                                    float* __restrict__ out) {
    __shared__ float tile[64 * 65];
    const int b    = blockIdx.x >> 7;          // 128 n-tiles per batch
    const int nb   = (blockIdx.x & 127) << 6;
    const int lane = threadIdx.x & 63;         // channel p in phase 1
    const int w    = threadIdx.x >> 6;         // wave 0..3

    const float bs = bias[lane];
#pragma unroll 4
    for (int t = 0; t < 16; ++t) {
        int nl = w * 16 + t;
        int n  = nb + nl;
        float acc = bs;
#pragma unroll
        for (int j = 0; j < D1; ++j) {
            float wj = ob[(b * D1 + j) * N_OUT + n];
            int   oj = off[(b * D1 + j) * N_OUT + n];
            acc += wj * fb[((size_t)b * HSZ + oj) * 64 + lane];
        }
        tile[lane * 65 + nl] = acc;
    }
    __syncthreads();
#pragma unroll
    for (int r = 0; r < 16; ++r) {
        int p = w * 16 + r;
        out[((size_t)(b * 64 + p)) * N_OUT + nb + lane] = tile[p * 65 + lane];
    }
}

// ---------------------------------------------------------------------------
extern "C" void kernel_launch(void* const* d_in, const int* in_sizes, int n_in,
                              void* d_out, int out_size, void* d_ws, size_t ws_size,
                              hipStream_t stream) {
    const float* features = (const float*)d_in[0];
    const float* in_bary  = (const float*)d_in[1];
    const int*   in_off   = (const int*)d_in[2];
    const int*   nbr      = (const int*)d_in[3];
    const float* out_bary = (const float*)d_in[4];
    const int*   out_off  = (const int*)d_in[5];
    const float* W0       = (const float*)d_in[6];
    const float* b0       = (const float*)d_in[7];
    const float* W1       = (const float*)d_in[8];
    const float* b1       = (const float*)d_in[9];
    const float* bias     = (const float*)d_in[10];

    float* ws    = (float*)d_ws;
    float* splat = ws + SPLAT_OFF;
    float* ones  = ws + ONES_OFF;
    float* W0t   = ws + W0T_OFF;
    float* W1t   = ws + W1T_OFF;
    float* fb    = ws + FB_OFF;

    // zero the scatter targets (ws is poisoned before every timed call)
    hipMemsetAsync(splat, 0, (size_t)(SPLAT_SZ + ONES_SZ) * sizeof(float), stream);

    transpose_w<<<(W0T_SZ + W1T_SZ) / 256, 256, 0, stream>>>(W0, W1, W0t, W1t);
    splat_kernel<<<NB * N_IN / 64, 256, 0, stream>>>(features, in_bary, in_off, splat, ones);
    normalize_kernel<<<SPLAT_SZ / 256, 256, 0, stream>>>(splat, ones);
    blur_kernel<<<NB * (HSZ / 64), 256, 0, stream>>>(splat, nbr, W0t, W1t, b0, b1, fb);
    slice_kernel<<<NB * (N_OUT / 64), 256, 0, stream>>>(fb, out_bary, out_off, bias, (float*)d_out);
}

// Round 2
// 255.474 us; speedup vs baseline: 2.6008x; 2.6008x over previous
//
#include <hip/hip_runtime.h>

#define NB 4          // batch
#define C_IN 64
#define N_IN 8192
#define N_OUT 8192
#define D1 4
#define FS 15
#define HSZ 16384     // max hash cnt
#define C_MID 64
#define C_OUT 64
#define LEAK 0.01f
#define CAP 24        // bucket capacity per vertex (lambda=2 Poisson, P(>24)~1e-18)

#define NVERT (NB*(HSZ+1))                  // 65,540 global vertices

// ---- workspace layout (float offsets) ----
// persistent region:
#define SPLAT_OFF  0
#define SPLAT_SZ   (NVERT*64)               // 4,194,560
#define W0T_OFF    (SPLAT_OFF + SPLAT_SZ)
#define W0T_SZ     (C_MID*C_IN*FS)          // 61,440
#define W1T_OFF    (W0T_OFF + W0T_SZ)
#define W1T_SZ     (C_OUT*C_MID)            // 4,096
// overlay region B: {featT, cnt, ent_id, ent_w} live only until gather_splat
// completes; fb (written by blur afterwards) aliases the same space.
#define BREG_OFF   (W1T_OFF + W1T_SZ)       // 4,260,096
#define FEATT_OFF  (BREG_OFF)
#define FEATT_SZ   (NB*N_IN*64)             // 2,097,152
#define CNT_OFF    (FEATT_OFF + FEATT_SZ)
#define CNT_SZ     (NVERT)                  // 65,540 (ints)
#define ENTID_OFF  (CNT_OFF + CNT_SZ)
#define ENT_SZ     (NVERT*CAP)              // 1,572,960
#define ENTW_OFF   (ENTID_OFF + ENT_SZ)
#define FB_OFF     (BREG_OFF)               // aliases featT+buckets (safe: dead)
#define FB_SZ      (NB*HSZ*64)              // 4,194,304

// ---------------------------------------------------------------------------
// W0t[f][c][o] = W0[o][c][f];  W1t[o][p] = W1[p][o]
__global__ __launch_bounds__(256) void transpose_w(const float* __restrict__ W0,
                                                   const float* __restrict__ W1,
                                                   float* __restrict__ W0t,
                                                   float* __restrict__ W1t) {
    int e = blockIdx.x * 256 + threadIdx.x;
    if (e < W0T_SZ) {
        int f = e / (64 * 64);
        int r = e % (64 * 64);
        int c = r >> 6;
        int o = r & 63;
        W0t[e] = W0[o * (C_IN * FS) + c * FS + f];
    } else {
        int e2 = e - W0T_SZ;   // < 4096
        int o = e2 >> 6, p = e2 & 63;
        W1t[e2] = W1[p * 64 + o];
    }
}

// ---------------------------------------------------------------------------
// featT[(b*N+n)*64 + c] = feat[(b*64+c)*N + n]   (LDS tile transpose)
__global__ __launch_bounds__(256) void transpose_feat(const float* __restrict__ feat,
                                                      float* __restrict__ featT) {
    __shared__ float t[64 * 65];
    const int b  = blockIdx.x >> 7;            // 128 n-tiles per batch
    const int nb = (blockIdx.x & 127) << 6;
    const int l  = threadIdx.x & 63;
    const int g  = threadIdx.x >> 6;
#pragma unroll
    for (int i = 0; i < 16; ++i) {
        int c = g * 16 + i;
        t[c * 65 + l] = feat[((size_t)(b * 64 + c)) * N_IN + nb + l];
    }
    __syncthreads();
#pragma unroll
    for (int i = 0; i < 16; ++i) {
        int n = g * 16 + i;
        featT[((size_t)(b * N_IN) + nb + n) * 64 + l] = t[l * 65 + n];
    }
}

// ---------------------------------------------------------------------------
// bucket fill: one thread per (b,j,n) entry; ~131K small int atomics.
__global__ __launch_bounds__(256) void fill_buckets(const int* __restrict__ off,
                                                    const float* __restrict__ bary,
                                                    int* __restrict__ cnt,
                                                    int* __restrict__ ent_id,
                                                    float* __restrict__ ent_w) {
    int e = blockIdx.x * 256 + threadIdx.x;    // < NB*D1*N_IN = 131072
    int v = off[e] + 1;                        // global vertex (incl. batch base)
    int n = e % N_IN;
    int b = e / (D1 * N_IN);
    int slot = atomicAdd(&cnt[v], 1);
    if (slot < CAP) {
        ent_id[v * CAP + slot] = b * N_IN + n;
        ent_w [v * CAP + slot] = bary[e];
    }
}

// ---------------------------------------------------------------------------
// gather-splat + fused normalize: one wave per vertex, lane = channel.
__global__ __launch_bounds__(256) void gather_splat(const float* __restrict__ featT,
                                                    const int* __restrict__ cnt,
                                                    const int* __restrict__ ent_id,
                                                    const float* __restrict__ ent_w,
                                                    float* __restrict__ splat) {
    const int v    = blockIdx.x * 4 + (threadIdx.x >> 6);   // vertex
    const int lane = threadIdx.x & 63;                      // channel
    int c = cnt[v];
    if (c > CAP) c = CAP;
    float acc = 0.f, sw = 0.f;
    for (int e = 0; e < c; ++e) {
        int   pt = ent_id[v * CAP + e];
        float wt = ent_w [v * CAP + e];
        acc += wt * featT[(size_t)pt * 64 + lane];
        sw  += wt;
    }
    splat[(size_t)v * 64 + lane] = acc / (sw + 1e-5f);
}

// ---------------------------------------------------------------------------
// blur: per block computes fb[b, hb..hb+63, 0..63] =
//   W1 @ leaky(W0 (x) gathered-splat + b0) + b1
// 256 threads, 4x4 micro-tile, LDS tiles padded to 68 dwords/row.
__global__ __launch_bounds__(256) void blur_kernel(const float* __restrict__ splat,
                                                   const int* __restrict__ nbr,
                                                   const float* __restrict__ W0t,
                                                   const float* __restrict__ W1t,
                                                   const float* __restrict__ b0,
                                                   const float* __restrict__ b1,
                                                   float* __restrict__ fb) {
    __shared__ float As[64 * 68];
    __shared__ float Xs[64 * 68];
    __shared__ float Hs[64 * 68];

    const int tid = threadIdx.x;
    const int b   = blockIdx.x >> 8;           // 256 h-tiles per batch
    const int hb  = (blockIdx.x & 255) << 6;

    const int to = tid & 15;                   // o/p micro-tile (4 each)
    const int th = tid >> 4;                   // h  micro-tile (4 each)

    const int s_o  = tid & 63;                 // A-staging: o lane
    const int s_cb = (tid >> 6) * 16;          // A-staging: c base
    const int x_hh = tid & 63;                 // X-staging: h lane
    const int x_cq = tid >> 6;                 // X-staging: c quarter

    const size_t bbase = (size_t)b * (HSZ + 1) * 64;

    float acc[4][4] = {};

    for (int f = 0; f < FS; ++f) {
        __syncthreads();
        // stage A: As[c][o] = W0t[f][c][o]  (coalesced)
        const float* w0f = W0t + f * 4096;
#pragma unroll
        for (int i = 0; i < 16; ++i) {
            int c = s_cb + i;
            As[c * 68 + s_o] = w0f[c * 64 + s_o];
        }
        // stage X: Xs[c][hh] = splat[b, nbr(f,hb+hh)+1, c]
        int v = nbr[((b * FS) + f) * HSZ + hb + x_hh] + 1;
        const float* row = splat + bbase + (size_t)v * 64;
#pragma unroll
        for (int i = 0; i < 4; ++i) {
            int c0 = x_cq * 16 + i * 4;
            float4 val = *(const float4*)(row + c0);
            Xs[(c0 + 0) * 68 + x_hh] = val.x;
            Xs[(c0 + 1) * 68 + x_hh] = val.y;
            Xs[(c0 + 2) * 68 + x_hh] = val.z;
            Xs[(c0 + 3) * 68 + x_hh] = val.w;
        }
        __syncthreads();
#pragma unroll 4
        for (int k = 0; k < 64; ++k) {
            const float4 a = *(const float4*)(As + k * 68 + (to << 2));
            const float4 x = *(const float4*)(Xs + k * 68 + (th << 2));
            acc[0][0] += a.x * x.x; acc[0][1] += a.x * x.y; acc[0][2] += a.x * x.z; acc[0][3] += a.x * x.w;
            acc[1][0] += a.y * x.x; acc[1][1] += a.y * x.y; acc[1][2] += a.y * x.z; acc[1][3] += a.y * x.w;
            acc[2][0] += a.z * x.x; acc[2][1] += a.z * x.y; acc[2][2] += a.z * x.z; acc[2][3] += a.z * x.w;
            acc[3][0] += a.w * x.x; acc[3][1] += a.w * x.y; acc[3][2] += a.w * x.z; acc[3][3] += a.w * x.w;
        }
    }

    __syncthreads();
    // bias + leaky -> Hs[o][hh]; restage As = W1t[o][p]
    float4 b0v = *(const float4*)(b0 + (to << 2));
    const float b0a[4] = {b0v.x, b0v.y, b0v.z, b0v.w};
#pragma unroll
    for (int i = 0; i < 4; ++i) {
        float4 hv;
        float v0 = acc[i][0] + b0a[i]; hv.x = v0 > 0.f ? v0 : LEAK * v0;
        float v1 = acc[i][1] + b0a[i]; hv.y = v1 > 0.f ? v1 : LEAK * v1;
        float v2 = acc[i][2] + b0a[i]; hv.z = v2 > 0.f ? v2 : LEAK * v2;
        float v3 = acc[i][3] + b0a[i]; hv.w = v3 > 0.f ? v3 : LEAK * v3;
        *(float4*)(Hs + (to * 4 + i) * 68 + (th << 2)) = hv;
    }
#pragma unroll
    for (int i = 0; i < 16; ++i) {
        int o = s_cb + i;
        As[o * 68 + s_o] = W1t[o * 64 + s_o];
    }
    __syncthreads();

    float acc2[4][4] = {};
#pragma unroll 4
    for (int k = 0; k < 64; ++k) {
        const float4 a = *(const float4*)(As + k * 68 + (to << 2));  // W1[p][k]
        const float4 x = *(const float4*)(Hs + k * 68 + (th << 2));
        acc2[0][0] += a.x * x.x; acc2[0][1] += a.x * x.y; acc2[0][2] += a.x * x.z; acc2[0][3] += a.x * x.w;
        acc2[1][0] += a.y * x.x; acc2[1][1] += a.y * x.y; acc2[1][2] += a.y * x.z; acc2[1][3] += a.y * x.w;
        acc2[2][0] += a.z * x.x; acc2[2][1] += a.z * x.y; acc2[2][2] += a.z * x.z; acc2[2][3] += a.z * x.w;
        acc2[3][0] += a.w * x.x; acc2[3][1] += a.w * x.y; acc2[3][2] += a.w * x.z; acc2[3][3] += a.w * x.w;
    }

    float4 b1v = *(const float4*)(b1 + (to << 2));
#pragma unroll
    for (int j = 0; j < 4; ++j) {
        int h = hb + (th << 2) + j;
        float4 o4;
        o4.x = acc2[0][j] + b1v.x;
        o4.y = acc2[1][j] + b1v.y;
        o4.z = acc2[2][j] + b1v.z;
        o4.w = acc2[3][j] + b1v.w;
        *(float4*)(fb + ((size_t)b * HSZ + h) * 64 + (to << 2)) = o4;
    }
}

// ---------------------------------------------------------------------------
// slice: out[b,p,n] = bias[p] + sum_j ob[b,j,n] * fb[b, off[b,j,n], p]
__global__ __launch_bounds__(256) void slice_kernel(const float* __restrict__ fb,
                                                    const float* __restrict__ ob,
                                                    const int* __restrict__ off,
                                                    const float* __restrict__ bias,
                                                    float* __restrict__ out) {
    __shared__ float tile[64 * 65];
    const int b    = blockIdx.x >> 7;          // 128 n-tiles per batch
    const int nb   = (blockIdx.x & 127) << 6;
    const int lane = threadIdx.x & 63;         // channel p in phase 1
    const int w    = threadIdx.x >> 6;         // wave 0..3

    const float bs = bias[lane];
#pragma unroll 4
    for (int t = 0; t < 16; ++t) {
        int nl = w * 16 + t;
        int n  = nb + nl;
        float acc = bs;
#pragma unroll
        for (int j = 0; j < D1; ++j) {
            float wj = ob[(b * D1 + j) * N_OUT + n];
            int   oj = off[(b * D1 + j) * N_OUT + n];
            acc += wj * fb[((size_t)b * HSZ + oj) * 64 + lane];
        }
        tile[lane * 65 + nl] = acc;
    }
    __syncthreads();
#pragma unroll
    for (int r = 0; r < 16; ++r) {
        int p = w * 16 + r;
        out[((size_t)(b * 64 + p)) * N_OUT + nb + lane] = tile[p * 65 + lane];
    }
}

// ---------------------------------------------------------------------------
extern "C" void kernel_launch(void* const* d_in, const int* in_sizes, int n_in,
                              void* d_out, int out_size, void* d_ws, size_t ws_size,
                              hipStream_t stream) {
    const float* features = (const float*)d_in[0];
    const float* in_bary  = (const float*)d_in[1];
    const int*   in_off   = (const int*)d_in[2];
    const int*   nbr      = (const int*)d_in[3];
    const float* out_bary = (const float*)d_in[4];
    const int*   out_off  = (const int*)d_in[5];
    const float* W0       = (const float*)d_in[6];
    const float* b0       = (const float*)d_in[7];
    const float* W1       = (const float*)d_in[8];
    const float* b1       = (const float*)d_in[9];
    const float* bias     = (const float*)d_in[10];

    float* ws     = (float*)d_ws;
    float* splat  = ws + SPLAT_OFF;
    float* W0t    = ws + W0T_OFF;
    float* W1t    = ws + W1T_OFF;
    float* featT  = ws + FEATT_OFF;
    int*   cnt    = (int*)(ws + CNT_OFF);
    int*   ent_id = (int*)(ws + ENTID_OFF);
    float* ent_w  = ws + ENTW_OFF;
    float* fb     = ws + FB_OFF;               // aliases featT/buckets (dead by then)

    // only the bucket counters need zeroing (256 KB)
    hipMemsetAsync(cnt, 0, (size_t)CNT_SZ * sizeof(int), stream);

    transpose_w<<<(W0T_SZ + W1T_SZ) / 256, 256, 0, stream>>>(W0, W1, W0t, W1t);
    transpose_feat<<<NB * (N_IN / 64), 256, 0, stream>>>(features, featT);
    fill_buckets<<<NB * D1 * N_IN / 256, 256, 0, stream>>>(in_off, in_bary, cnt, ent_id, ent_w);
    gather_splat<<<NVERT / 4, 256, 0, stream>>>(featT, cnt, ent_id, ent_w, splat);
    blur_kernel<<<NB * (HSZ / 64), 256, 0, stream>>>(splat, nbr, W0t, W1t, b0, b1, fb);
    slice_kernel<<<NB * (N_OUT / 64), 256, 0, stream>>>(fb, out_bary, out_off, bias, (float*)d_out);
}

// Round 3
// 149.270 us; speedup vs baseline: 4.4512x; 1.7115x over previous
//
#include <hip/hip_runtime.h>

#define NB 4
#define C_IN 64
#define N_IN 8192
#define N_OUT 8192
#define D1 4
#define FS 15
#define HSZ 16384
#define C_MID 64
#define C_OUT 64
#define LEAK 0.01f
#define CAP 24

#define NVERT (NB*(HSZ+1))                  // 65,540

typedef __attribute__((ext_vector_type(8))) short short8;
typedef __attribute__((ext_vector_type(4))) float floatx4;

// ---- workspace layout (float-unit offsets) ----
#define SPLATB_OFF 0
#define SPLATB_FL  (NVERT*32)               // bf16 table: 65540*64 ushort = 2,097,280 fl
#define W0B_OFF    (SPLATB_OFF + SPLATB_FL)
#define W0B_FL     (C_MID*C_IN*FS/2)        // 30,720
#define W1B_OFF    (W0B_OFF + W0B_FL)
#define W1B_FL     (C_OUT*C_MID/2)          // 2,048
#define BREG_OFF   (W1B_OFF + W1B_FL)
// overlay A: featB + buckets (dead after gather_splat)
#define FEATB_OFF  (BREG_OFF)
#define FEATB_FL   (NB*N_IN*32)             // 1,048,576
#define CNT_OFF    (FEATB_OFF + FEATB_FL)
#define CNT_FL     (NVERT)
#define ENTID_OFF  (CNT_OFF + CNT_FL)
#define ENT_FL     (NVERT*CAP)
#define ENTW_OFF   (ENTID_OFF + ENT_FL)
// overlay B: fb (bf16), written by blur after overlay A is dead
#define FB_OFF     (BREG_OFF)
#define FB_FL      (NB*HSZ*32)              // 2,097,152

// round-to-nearest-even fp32 -> bf16 bits
__device__ inline ushort f2bf(float x) {
    uint u = __float_as_uint(x);
    return (ushort)((u + 0x7FFF + ((u >> 16) & 1)) >> 16);
}
__device__ inline float bf2f(ushort b) {
    return __uint_as_float(((uint)b) << 16);
}

// ---------------------------------------------------------------------------
// W0b[f][o][c] = bf16(W0[o][c][f]);  W1b[p][o] = bf16(W1[p][o])
__global__ __launch_bounds__(256) void transpose_w(const float* __restrict__ W0,
                                                   const float* __restrict__ W1,
                                                   ushort* __restrict__ W0b,
                                                   ushort* __restrict__ W1b) {
    int e = blockIdx.x * 256 + threadIdx.x;
    if (e < C_MID * C_IN * FS) {
        int f = e >> 12;            // e / 4096
        int o = (e >> 6) & 63;
        int c = e & 63;
        W0b[e] = f2bf(W0[(o * 64 + c) * FS + f]);
    } else {
        int e2 = e - C_MID * C_IN * FS;   // < 4096
        W1b[e2] = f2bf(W1[e2]);
    }
}

// ---------------------------------------------------------------------------
// featB[(b*N+n)*64 + c] = bf16(feat[(b*64+c)*N + n])
__global__ __launch_bounds__(256) void transpose_feat(const float* __restrict__ feat,
                                                      ushort* __restrict__ featB) {
    __shared__ float t[64 * 65];
    const int b  = blockIdx.x >> 7;
    const int nb = (blockIdx.x & 127) << 6;
    const int l  = threadIdx.x & 63;
    const int g  = threadIdx.x >> 6;
#pragma unroll
    for (int i = 0; i < 16; ++i) {
        int c = g * 16 + i;
        t[c * 65 + l] = feat[((size_t)(b * 64 + c)) * N_IN + nb + l];
    }
    __syncthreads();
#pragma unroll
    for (int i = 0; i < 16; ++i) {
        int n = g * 16 + i;
        featB[((size_t)(b * N_IN) + nb + n) * 64 + l] = f2bf(t[l * 65 + n]);
    }
}

// ---------------------------------------------------------------------------
__global__ __launch_bounds__(256) void fill_buckets(const int* __restrict__ off,
                                                    const float* __restrict__ bary,
                                                    int* __restrict__ cnt,
                                                    int* __restrict__ ent_id,
                                                    float* __restrict__ ent_w) {
    int e = blockIdx.x * 256 + threadIdx.x;    // < NB*D1*N_IN
    int v = off[e] + 1;
    int n = e % N_IN;
    int b = e / (D1 * N_IN);
    int slot = atomicAdd(&cnt[v], 1);
    if (slot < CAP) {
        ent_id[v * CAP + slot] = b * N_IN + n;
        ent_w [v * CAP + slot] = bary[e];
    }
}

// ---------------------------------------------------------------------------
// gather-splat + fused normalize; one wave per vertex, lane = channel; bf16 out.
__global__ __launch_bounds__(256) void gather_splat(const ushort* __restrict__ featB,
                                                    const int* __restrict__ cnt,
                                                    const int* __restrict__ ent_id,
                                                    const float* __restrict__ ent_w,
                                                    ushort* __restrict__ splatB) {
    const int v    = blockIdx.x * 4 + (threadIdx.x >> 6);
    const int lane = threadIdx.x & 63;
    int c = cnt[v];
    if (c > CAP) c = CAP;
    float acc = 0.f, sw = 0.f;
    for (int e = 0; e < c; ++e) {
        int   pt = ent_id[v * CAP + e];
        float wt = ent_w [v * CAP + e];
        acc += wt * bf2f(featB[(size_t)pt * 64 + lane]);
        sw  += wt;
    }
    splatB[(size_t)v * 64 + lane] = f2bf(acc / (sw + 1e-5f));
}

// ---------------------------------------------------------------------------
// blur via bf16 MFMA. Per block: 64 h x 64 o tile.
// LDS rows padded to 72 ushorts (144 B) -> <=2-way bank aliasing (free).
#define LSTR 72
__global__ __launch_bounds__(256) void blur_mfma(const ushort* __restrict__ splatB,
                                                 const int* __restrict__ nbr,
                                                 const ushort* __restrict__ W0b,
                                                 const ushort* __restrict__ W1b,
                                                 const float* __restrict__ b0,
                                                 const float* __restrict__ b1,
                                                 ushort* __restrict__ fb) {
    __shared__ ushort As[64 * LSTR];
    __shared__ ushort Xs[64 * LSTR];
    __shared__ ushort Hs[64 * LSTR];

    const int tid = threadIdx.x;
    // XCD swizzle: batch b pinned to XCDs {b, b+4} (blockIdx%8 ~ XCD heuristic)
    const int p  = blockIdx.x;
    const int b  = p & 3;
    const int hb = (((p >> 3) << 1) + ((p >> 2) & 1)) << 6;

    const int lane = tid & 63;
    const int w    = tid >> 6;     // wave = o/p 16-tile
    const int m    = lane & 15;
    const int q    = lane >> 4;

    const int srow = tid >> 3;     // staging: 32 rows per pass
    const int sseg = (tid & 7) * 8;

    floatx4 acc[4] = {};

    for (int f = 0; f < FS; ++f) {
        __syncthreads();
        const ushort* w0f  = W0b + f * 4096;
        const int*    nrow = nbr + ((b * FS) + f) * HSZ + hb;
#pragma unroll
        for (int i = 0; i < 2; ++i) {
            int r = i * 32 + srow;
            *(short8*)&As[r * LSTR + sseg] = *(const short8*)&w0f[r * 64 + sseg];
            int v = nrow[r] + 1;
            *(short8*)&Xs[r * LSTR + sseg] =
                *(const short8*)&splatB[((size_t)(b * (HSZ + 1) + v)) * 64 + sseg];
        }
        __syncthreads();
#pragma unroll
        for (int ch = 0; ch < 2; ++ch) {
            int ko = ch * 32 + q * 8;
            short8 a = *(const short8*)&As[(w * 16 + m) * LSTR + ko];
#pragma unroll
            for (int t = 0; t < 4; ++t) {
                short8 bb = *(const short8*)&Xs[(t * 16 + m) * LSTR + ko];
                acc[t] = __builtin_amdgcn_mfma_f32_16x16x32_bf16(a, bb, acc[t], 0, 0, 0);
            }
        }
    }

    __syncthreads();   // all As/Xs reads done
    // restage As <- W1b[p][o]
#pragma unroll
    for (int i = 0; i < 2; ++i) {
        int r = i * 32 + srow;
        *(short8*)&As[r * LSTR + sseg] = *(const short8*)&W1b[r * 64 + sseg];
    }
    // bias + leaky -> Hs[h][o] (bf16). C/D layout: col(h)=lane&15, row(o)=q*4+reg.
    {
        const float4 b0v = *(const float4*)(b0 + w * 16 + q * 4);
#pragma unroll
        for (int t = 0; t < 4; ++t) {
            float v0 = acc[t][0] + b0v.x; v0 = v0 > 0.f ? v0 : LEAK * v0;
            float v1 = acc[t][1] + b0v.y; v1 = v1 > 0.f ? v1 : LEAK * v1;
            float v2 = acc[t][2] + b0v.z; v2 = v2 > 0.f ? v2 : LEAK * v2;
            float v3 = acc[t][3] + b0v.w; v3 = v3 > 0.f ? v3 : LEAK * v3;
            ushort4 hv;
            hv.x = f2bf(v0); hv.y = f2bf(v1); hv.z = f2bf(v2); hv.w = f2bf(v3);
            *(ushort4*)&Hs[(t * 16 + m) * LSTR + w * 16 + q * 4] = hv;
        }
    }
    __syncthreads();

    floatx4 acc2[4] = {};
#pragma unroll
    for (int ch = 0; ch < 2; ++ch) {
        int ko = ch * 32 + q * 8;
        short8 a2 = *(const short8*)&As[(w * 16 + m) * LSTR + ko];   // W1[p][o]
#pragma unroll
        for (int t = 0; t < 4; ++t) {
            short8 b2 = *(const short8*)&Hs[(t * 16 + m) * LSTR + ko];
            acc2[t] = __builtin_amdgcn_mfma_f32_16x16x32_bf16(a2, b2, acc2[t], 0, 0, 0);
        }
    }

    __syncthreads();   // Hs/As reads done; Xs reused as transpose buffer
    {
        const float4 b1v = *(const float4*)(b1 + w * 16 + q * 4);
#pragma unroll
        for (int t = 0; t < 4; ++t) {
            ushort4 ov;
            ov.x = f2bf(acc2[t][0] + b1v.x);
            ov.y = f2bf(acc2[t][1] + b1v.y);
            ov.z = f2bf(acc2[t][2] + b1v.z);
            ov.w = f2bf(acc2[t][3] + b1v.w);
            *(ushort4*)&Xs[(t * 16 + m) * LSTR + w * 16 + q * 4] = ov;  // Ts[h][p]
        }
    }
    __syncthreads();
#pragma unroll
    for (int i = 0; i < 2; ++i) {
        int r = i * 32 + srow;
        *(short8*)&fb[((size_t)(b * HSZ) + hb + r) * 64 + sseg] =
            *(const short8*)&Xs[r * LSTR + sseg];
    }
}

// ---------------------------------------------------------------------------
// slice: out[b,p,n] = bias[p] + sum_j ob[b,j,n] * bf2f(fb[b, off[b,j,n], p])
__global__ __launch_bounds__(256) void slice_kernel(const ushort* __restrict__ fb,
                                                    const float* __restrict__ ob,
                                                    const int* __restrict__ off,
                                                    const float* __restrict__ bias,
                                                    float* __restrict__ out) {
    __shared__ float tile[64 * 65];
    const int b    = blockIdx.x >> 7;
    const int nb   = (blockIdx.x & 127) << 6;
    const int lane = threadIdx.x & 63;
    const int w    = threadIdx.x >> 6;

    const float bs = bias[lane];
#pragma unroll 4
    for (int t = 0; t < 16; ++t) {
        int nl = w * 16 + t;
        int n  = nb + nl;
        float acc = bs;
#pragma unroll
        for (int j = 0; j < D1; ++j) {
            float wj = ob[(b * D1 + j) * N_OUT + n];
            int   oj = off[(b * D1 + j) * N_OUT + n];
            acc += wj * bf2f(fb[((size_t)b * HSZ + oj) * 64 + lane]);
        }
        tile[lane * 65 + nl] = acc;
    }
    __syncthreads();
#pragma unroll
    for (int r = 0; r < 16; ++r) {
        int p = w * 16 + r;
        out[((size_t)(b * 64 + p)) * N_OUT + nb + lane] = tile[p * 65 + lane];
    }
}

// ---------------------------------------------------------------------------
extern "C" void kernel_launch(void* const* d_in, const int* in_sizes, int n_in,
                              void* d_out, int out_size, void* d_ws, size_t ws_size,
                              hipStream_t stream) {
    const float* features = (const float*)d_in[0];
    const float* in_bary  = (const float*)d_in[1];
    const int*   in_off   = (const int*)d_in[2];
    const int*   nbr      = (const int*)d_in[3];
    const float* out_bary = (const float*)d_in[4];
    const int*   out_off  = (const int*)d_in[5];
    const float* W0       = (const float*)d_in[6];
    const float* b0       = (const float*)d_in[7];
    const float* W1       = (const float*)d_in[8];
    const float* b1       = (const float*)d_in[9];
    const float* bias     = (const float*)d_in[10];

    float*  ws     = (float*)d_ws;
    ushort* splatB = (ushort*)(ws + SPLATB_OFF);
    ushort* W0b    = (ushort*)(ws + W0B_OFF);
    ushort* W1b    = (ushort*)(ws + W1B_OFF);
    ushort* featB  = (ushort*)(ws + FEATB_OFF);
    int*    cnt    = (int*)(ws + CNT_OFF);
    int*    ent_id = (int*)(ws + ENTID_OFF);
    float*  ent_w  = ws + ENTW_OFF;
    ushort* fb     = (ushort*)(ws + FB_OFF);   // aliases featB/buckets (dead by then)

    hipMemsetAsync(cnt, 0, (size_t)CNT_FL * sizeof(int), stream);

    transpose_w<<<(C_MID * C_IN * FS + C_OUT * C_MID) / 256, 256, 0, stream>>>(W0, W1, W0b, W1b);
    transpose_feat<<<NB * (N_IN / 64), 256, 0, stream>>>(features, featB);
    fill_buckets<<<NB * D1 * N_IN / 256, 256, 0, stream>>>(in_off, in_bary, cnt, ent_id, ent_w);
    gather_splat<<<NVERT / 4, 256, 0, stream>>>(featB, cnt, ent_id, ent_w, splatB);
    blur_mfma<<<NB * (HSZ / 64), 256, 0, stream>>>(splatB, nbr, W0b, W1b, b0, b1, fb);
    slice_kernel<<<NB * (N_OUT / 64), 256, 0, stream>>>(fb, out_bary, out_off, bias, (float*)d_out);
}

// Round 4
// 140.539 us; speedup vs baseline: 4.7277x; 1.0621x over previous
//
#include <hip/hip_runtime.h>

#define NB 4
#define C_IN 64
#define N_IN 8192
#define N_OUT 8192
#define D1 4
#define FS 15
#define HSZ 16384
#define C_MID 64
#define C_OUT 64
#define LEAK 0.01f
#define CAP 24

#define NVERT (NB*(HSZ+1))                  // 65,540

typedef __attribute__((ext_vector_type(8))) short short8;
typedef __attribute__((ext_vector_type(4))) float floatx4;

// ---- workspace layout (float-unit offsets) ----
#define SPLATB_OFF 0
#define SPLATB_FL  (NVERT*32)
#define W0B_OFF    (SPLATB_OFF + SPLATB_FL)
#define W0B_FL     (C_MID*C_IN*FS/2)
#define W1B_OFF    (W0B_OFF + W0B_FL)
#define W1B_FL     (C_OUT*C_MID/2)
#define BREG_OFF   (W1B_OFF + W1B_FL)
// overlay A: featB + buckets (dead after gather_splat)
#define FEATB_OFF  (BREG_OFF)
#define FEATB_FL   (NB*N_IN*32)
#define CNT_OFF    (FEATB_OFF + FEATB_FL)
#define CNT_FL     (NVERT)
#define ENTID_OFF  (CNT_OFF + CNT_FL)
#define ENT_FL     (NVERT*CAP)
#define ENTW_OFF   (ENTID_OFF + ENT_FL)
// overlay B: fb (bf16) aliases overlay A
#define FB_OFF     (BREG_OFF)
#define FB_FL      (NB*HSZ*32)

__device__ inline ushort f2bf(float x) {
    uint u = __float_as_uint(x);
    return (ushort)((u + 0x7FFF + ((u >> 16) & 1)) >> 16);
}
__device__ inline float bf2f(ushort b) {
    return __uint_as_float(((uint)b) << 16);
}

// ---------------------------------------------------------------------------
// fused prep: blocks [0,512) transpose features; [512,1024) fill buckets;
// [1024,1280) transpose weights. (independent work, one launch)
__global__ __launch_bounds__(256) void prep(const float* __restrict__ feat,
                                            const float* __restrict__ W0,
                                            const float* __restrict__ W1,
                                            const int* __restrict__ off,
                                            const float* __restrict__ bary,
                                            ushort* __restrict__ featB,
                                            ushort* __restrict__ W0b,
                                            ushort* __restrict__ W1b,
                                            int* __restrict__ cnt,
                                            int* __restrict__ ent_id,
                                            float* __restrict__ ent_w) {
    __shared__ float t[64 * 65];
    const int blk = blockIdx.x;
    const int tid = threadIdx.x;
    if (blk < 512) {
        // featB[(b*N+n)*64 + c] = bf16(feat[(b*64+c)*N + n])
        const int b  = blk >> 7;
        const int nb = (blk & 127) << 6;
        const int l  = tid & 63;
        const int g  = tid >> 6;
#pragma unroll
        for (int i = 0; i < 16; ++i) {
            int c = g * 16 + i;
            t[c * 65 + l] = feat[((size_t)(b * 64 + c)) * N_IN + nb + l];
        }
        __syncthreads();
#pragma unroll
        for (int i = 0; i < 16; ++i) {
            int n = g * 16 + i;
            featB[((size_t)(b * N_IN) + nb + n) * 64 + l] = f2bf(t[l * 65 + n]);
        }
    } else if (blk < 1024) {
        int e = (blk - 512) * 256 + tid;       // < NB*D1*N_IN
        int v = off[e] + 1;
        int n = e % N_IN;
        int b = e / (D1 * N_IN);
        int slot = atomicAdd(&cnt[v], 1);
        if (slot < CAP) {
            ent_id[v * CAP + slot] = b * N_IN + n;
            ent_w [v * CAP + slot] = bary[e];
        }
    } else {
        int e = (blk - 1024) * 256 + tid;      // < 65536
        if (e < C_MID * C_IN * FS) {
            int f = e >> 12;
            int o = (e >> 6) & 63;
            int c = e & 63;
            W0b[e] = f2bf(W0[(o * 64 + c) * FS + f]);   // W0b[f][o][c]
        } else {
            int e2 = e - C_MID * C_IN * FS;
            W1b[e2] = f2bf(W1[e2]);                     // W1b[p][o]
        }
    }
}

// ---------------------------------------------------------------------------
// gather-splat + fused normalize; one wave per vertex, lane = channel.
__global__ __launch_bounds__(256) void gather_splat(const ushort* __restrict__ featB,
                                                    const int* __restrict__ cnt,
                                                    const int* __restrict__ ent_id,
                                                    const float* __restrict__ ent_w,
                                                    ushort* __restrict__ splatB) {
    const int v    = blockIdx.x * 4 + (threadIdx.x >> 6);
    const int lane = threadIdx.x & 63;
    int c = cnt[v];
    if (c > CAP) c = CAP;
    float acc = 0.f, sw = 0.f;
    for (int e = 0; e < c; ++e) {
        int   pt = ent_id[v * CAP + e];
        float wt = ent_w [v * CAP + e];
        acc += wt * bf2f(featB[(size_t)pt * 64 + lane]);
        sw  += wt;
    }
    splatB[(size_t)v * 64 + lane] = f2bf(acc / (sw + 1e-5f));
}

// ---------------------------------------------------------------------------
// blur via bf16 MFMA, 64h x 64o tile/block, double-buffered single-barrier
// K-loop with 2-iteration index prefetch. LSTR=80 -> all LDS ops <=2-way.
#define LSTR 80
__global__ __launch_bounds__(256, 4) void blur_mfma(const ushort* __restrict__ splatB,
                                                    const int* __restrict__ nbr,
                                                    const ushort* __restrict__ W0b,
                                                    const ushort* __restrict__ W1b,
                                                    const float* __restrict__ b0,
                                                    const float* __restrict__ b1,
                                                    ushort* __restrict__ fb) {
    __shared__ ushort As[2][64 * LSTR];
    __shared__ ushort Xs[2][64 * LSTR];

    const int tid = threadIdx.x;
    const int p   = blockIdx.x;
    const int b   = p & 3;                    // batch <-> XCD pinning
    const int hb  = (p >> 2) << 6;

    const int lane = tid & 63;
    const int w    = tid >> 6;                // wave = o/p 16-tile
    const int m    = lane & 15;
    const int q    = lane >> 4;

    const int r0   = tid >> 3;                // staging rows (2 per thread)
    const int r1   = r0 + 32;
    const int sseg = (tid & 7) * 8;           // 16B segment within 128B row

    const int* nbase = nbr + (b * FS) * HSZ + hb;
    const size_t sbase = (size_t)b * (HSZ + 1) * 64;

    // ---- prologue: stage f=0, prefetch nbr indices for f=1 ----
    {
        int v0 = nbase[r0] + 1, v1 = nbase[r1] + 1;
        *(short8*)&As[0][r0 * LSTR + sseg] = *(const short8*)&W0b[r0 * 64 + sseg];
        *(short8*)&As[0][r1 * LSTR + sseg] = *(const short8*)&W0b[r1 * 64 + sseg];
        *(short8*)&Xs[0][r0 * LSTR + sseg] = *(const short8*)&splatB[sbase + (size_t)v0 * 64 + sseg];
        *(short8*)&Xs[0][r1 * LSTR + sseg] = *(const short8*)&splatB[sbase + (size_t)v1 * 64 + sseg];
    }
    int nv0 = nbase[HSZ + r0] + 1;
    int nv1 = nbase[HSZ + r1] + 1;
    __syncthreads();

    floatx4 acc[4] = {};

#pragma unroll
    for (int f = 0; f < FS; ++f) {
        const int cur = f & 1, nxt = cur ^ 1;
        short8 pa0, pa1, px0, px1;
        int nn0 = 0, nn1 = 0;
        if (f < FS - 1) {
            const ushort* w0n = W0b + (f + 1) * 4096;
            pa0 = *(const short8*)&w0n[r0 * 64 + sseg];
            pa1 = *(const short8*)&w0n[r1 * 64 + sseg];
            px0 = *(const short8*)&splatB[sbase + (size_t)nv0 * 64 + sseg];
            px1 = *(const short8*)&splatB[sbase + (size_t)nv1 * 64 + sseg];
            if (f < FS - 2) {
                nn0 = nbase[(f + 2) * HSZ + r0] + 1;
                nn1 = nbase[(f + 2) * HSZ + r1] + 1;
            }
        }
#pragma unroll
        for (int ch = 0; ch < 2; ++ch) {
            const int ko = ch * 32 + q * 8;
            short8 a = *(const short8*)&As[cur][(w * 16 + m) * LSTR + ko];
#pragma unroll
            for (int t = 0; t < 4; ++t) {
                short8 bb = *(const short8*)&Xs[cur][(t * 16 + m) * LSTR + ko];
                acc[t] = __builtin_amdgcn_mfma_f32_16x16x32_bf16(a, bb, acc[t], 0, 0, 0);
            }
        }
        if (f < FS - 1) {
            *(short8*)&As[nxt][r0 * LSTR + sseg] = pa0;
            *(short8*)&As[nxt][r1 * LSTR + sseg] = pa1;
            *(short8*)&Xs[nxt][r0 * LSTR + sseg] = px0;
            *(short8*)&Xs[nxt][r1 * LSTR + sseg] = px1;
            nv0 = nn0; nv1 = nn1;
        }
        __syncthreads();
    }

    // ---- second GEMM: W1 @ leaky(acc + b0) ----
    // restage As[0] <- W1b[p][o]; Hs (bias+leaky, bf16) -> Xs[0][h][o]
    *(short8*)&As[0][r0 * LSTR + sseg] = *(const short8*)&W1b[r0 * 64 + sseg];
    *(short8*)&As[0][r1 * LSTR + sseg] = *(const short8*)&W1b[r1 * 64 + sseg];
    {
        const float4 b0v = *(const float4*)(b0 + w * 16 + q * 4);
#pragma unroll
        for (int t = 0; t < 4; ++t) {
            float v0 = acc[t][0] + b0v.x; v0 = v0 > 0.f ? v0 : LEAK * v0;
            float v1 = acc[t][1] + b0v.y; v1 = v1 > 0.f ? v1 : LEAK * v1;
            float v2 = acc[t][2] + b0v.z; v2 = v2 > 0.f ? v2 : LEAK * v2;
            float v3 = acc[t][3] + b0v.w; v3 = v3 > 0.f ? v3 : LEAK * v3;
            ushort4 hv;
            hv.x = f2bf(v0); hv.y = f2bf(v1); hv.z = f2bf(v2); hv.w = f2bf(v3);
            *(ushort4*)&Xs[0][(t * 16 + m) * LSTR + w * 16 + q * 4] = hv;
        }
    }
    __syncthreads();

    floatx4 acc2[4] = {};
#pragma unroll
    for (int ch = 0; ch < 2; ++ch) {
        const int ko = ch * 32 + q * 8;
        short8 a2 = *(const short8*)&As[0][(w * 16 + m) * LSTR + ko];
#pragma unroll
        for (int t = 0; t < 4; ++t) {
            short8 b2 = *(const short8*)&Xs[0][(t * 16 + m) * LSTR + ko];
            acc2[t] = __builtin_amdgcn_mfma_f32_16x16x32_bf16(a2, b2, acc2[t], 0, 0, 0);
        }
    }

    // transpose out via Xs[1]: Ts[h][p], then coalesced row stores
    {
        const float4 b1v = *(const float4*)(b1 + w * 16 + q * 4);
#pragma unroll
        for (int t = 0; t < 4; ++t) {
            ushort4 ov;
            ov.x = f2bf(acc2[t][0] + b1v.x);
            ov.y = f2bf(acc2[t][1] + b1v.y);
            ov.z = f2bf(acc2[t][2] + b1v.z);
            ov.w = f2bf(acc2[t][3] + b1v.w);
            *(ushort4*)&Xs[1][(t * 16 + m) * LSTR + w * 16 + q * 4] = ov;
        }
    }
    __syncthreads();
    *(short8*)&fb[((size_t)(b * HSZ) + hb + r0) * 64 + sseg] = *(const short8*)&Xs[1][r0 * LSTR + sseg];
    *(short8*)&fb[((size_t)(b * HSZ) + hb + r1) * 64 + sseg] = *(const short8*)&Xs[1][r1 * LSTR + sseg];
}

// ---------------------------------------------------------------------------
// slice: out[b,p,n] = bias[p] + sum_j ob[b,j,n] * bf2f(fb[b, off[b,j,n], p])
// batch <-> XCD pinning via b = blk & 3 (fb slice 2.1 MB fits per-XCD L2).
__global__ __launch_bounds__(256) void slice_kernel(const ushort* __restrict__ fb,
                                                    const float* __restrict__ ob,
                                                    const int* __restrict__ off,
                                                    const float* __restrict__ bias,
                                                    float* __restrict__ out) {
    __shared__ float tile[64 * 65];
    const int blk  = blockIdx.x;
    const int b    = blk & 3;
    const int nb   = (blk >> 2) << 6;
    const int lane = threadIdx.x & 63;
    const int w    = threadIdx.x >> 6;

    const float bs = bias[lane];
#pragma unroll 4
    for (int t = 0; t < 16; ++t) {
        int nl = w * 16 + t;
        int n  = nb + nl;
        float acc = bs;
#pragma unroll
        for (int j = 0; j < D1; ++j) {
            float wj = ob[(b * D1 + j) * N_OUT + n];
            int   oj = off[(b * D1 + j) * N_OUT + n];
            acc += wj * bf2f(fb[((size_t)b * HSZ + oj) * 64 + lane]);
        }
        tile[lane * 65 + nl] = acc;
    }
    __syncthreads();
#pragma unroll
    for (int r = 0; r < 16; ++r) {
        int p = w * 16 + r;
        out[((size_t)(b * 64 + p)) * N_OUT + nb + lane] = tile[p * 65 + lane];
    }
}

// ---------------------------------------------------------------------------
extern "C" void kernel_launch(void* const* d_in, const int* in_sizes, int n_in,
                              void* d_out, int out_size, void* d_ws, size_t ws_size,
                              hipStream_t stream) {
    const float* features = (const float*)d_in[0];
    const float* in_bary  = (const float*)d_in[1];
    const int*   in_off   = (const int*)d_in[2];
    const int*   nbr      = (const int*)d_in[3];
    const float* out_bary = (const float*)d_in[4];
    const int*   out_off  = (const int*)d_in[5];
    const float* W0       = (const float*)d_in[6];
    const float* b0       = (const float*)d_in[7];
    const float* W1       = (const float*)d_in[8];
    const float* b1       = (const float*)d_in[9];
    const float* bias     = (const float*)d_in[10];

    float*  ws     = (float*)d_ws;
    ushort* splatB = (ushort*)(ws + SPLATB_OFF);
    ushort* W0b    = (ushort*)(ws + W0B_OFF);
    ushort* W1b    = (ushort*)(ws + W1B_OFF);
    ushort* featB  = (ushort*)(ws + FEATB_OFF);
    int*    cnt    = (int*)(ws + CNT_OFF);
    int*    ent_id = (int*)(ws + ENTID_OFF);
    float*  ent_w  = ws + ENTW_OFF;
    ushort* fb     = (ushort*)(ws + FB_OFF);

    hipMemsetAsync(cnt, 0, (size_t)CNT_FL * sizeof(int), stream);

    prep<<<1280, 256, 0, stream>>>(features, W0, W1, in_off, in_bary,
                                   featB, W0b, W1b, cnt, ent_id, ent_w);
    gather_splat<<<NVERT / 4, 256, 0, stream>>>(featB, cnt, ent_id, ent_w, splatB);
    blur_mfma<<<NB * (HSZ / 64), 256, 0, stream>>>(splatB, nbr, W0b, W1b, b0, b1, fb);
    slice_kernel<<<NB * (N_OUT / 64), 256, 0, stream>>>(fb, out_bary, out_off, bias, (float*)d_out);
}